// Round 9
// baseline (277.820 us; speedup 1.0000x reference)
//
#include <hip/hip_runtime.h>
#include <math.h>

static constexpr int N = 50000;
static constexpr int E = 800000;
static constexpr int D = 128;      // D_IN = D_HID
static constexpr int DO = 64;      // D_OUT
static constexpr int NB = (N + 255) / 256;   // 196 scan blocks
static constexpr int KSH = 8;                // histogram shards (src >> 13 -> 0..6)

// ---- bf16 helpers ----
__device__ __forceinline__ unsigned pack_bf16(float a, float b) {
  unsigned ua = __float_as_uint(a), ub = __float_as_uint(b);
  ua = (ua + 0x7FFFu + ((ua >> 16) & 1u)) >> 16;
  ub = (ub + 0x7FFFu + ((ub >> 16) & 1u)) >> 16;
  return ua | (ub << 16);
}
__device__ __forceinline__ float blo(unsigned u) { return __uint_as_float(u << 16); }
__device__ __forceinline__ float bhi(unsigned u) { return __uint_as_float(u & 0xFFFF0000u); }

// ---------------- zero sharded histogram ----------------
__global__ __launch_bounds__(256) void k_zero(unsigned long long* __restrict__ packed_sh) {
  int g = blockIdx.x * 256 + threadIdx.x;
  if (g < KSH * N) packed_sh[g] = 0ULL;
}

// ---------------- sharded degree+count histogram (shard = src >> 13) ----------------
// packed_sh[k][i] = (cnt << 48) | sum_fix48(ew * 2^31); pos[e] = per-(shard,dst) slot
__global__ __launch_bounds__(256) void k_hist(const int* __restrict__ src,
                                              const int* __restrict__ dst,
                                              const float* __restrict__ ew,
                                              unsigned long long* __restrict__ packed_sh,
                                              int* __restrict__ pos) {
  int e = blockIdx.x * 256 + threadIdx.x;
  if (e < E) {
    int k = src[e] >> 13;
    unsigned wfix = (unsigned)(ew[e] * 2147483648.0f + 0.5f);
    unsigned long long inc = (1ULL << 48) | (unsigned long long)wfix;
    unsigned long long old = __hip_atomic_fetch_add(&packed_sh[(size_t)k * N + dst[e]], inc,
                                                    __ATOMIC_RELAXED, __HIP_MEMORY_SCOPE_AGENT);
    pos[e] = (int)(old >> 48);
  }
}

// fold shards: dinv, total cnt, per-shard exclusive bases (local), block partials
__global__ __launch_bounds__(256) void k_scan1(const unsigned long long* __restrict__ packed_sh,
                                               float* __restrict__ dinv,
                                               int* __restrict__ cnt_out,
                                               int* __restrict__ shard_base,
                                               int* __restrict__ partial) {
  __shared__ int sm[256];
  int i = blockIdx.x * 256 + threadIdx.x;
  int t = threadIdx.x;
  int c = 0;
  if (i < N) {
    unsigned long long wtot = 0;
    int run = 0;
#pragma unroll
    for (int k = 0; k < KSH; ++k) {
      unsigned long long v = packed_sh[(size_t)k * N + i];
      shard_base[(size_t)k * N + i] = run;
      run += (int)(v >> 48);
      wtot += (v & 0x0000FFFFFFFFFFFFULL);
    }
    c = run;
    float deg = 1.0f + (float)((double)wtot * (1.0 / 2147483648.0));
    dinv[i] = 1.0f / sqrtf(deg);
    cnt_out[i] = c;
  }
  sm[t] = c;
  __syncthreads();
#pragma unroll
  for (int off = 128; off > 0; off >>= 1) {
    if (t < off) sm[t] += sm[t + off];
    __syncthreads();
  }
  if (t == 0) partial[blockIdx.x] = sm[0];
}

// cast x -> bhs = bf16(x * dinv[node])   (scaled-feature storage)
__global__ __launch_bounds__(256) void k_cast(const float* __restrict__ x,
                                              const float* __restrict__ dinv,
                                              unsigned* __restrict__ outb) {
  int g = blockIdx.x * 256 + threadIdx.x;   // over N*64
  if (g < N * 64) {
    float dv = dinv[g >> 6];
    float2 v = ((const float2*)x)[g];
    outb[g] = pack_bf16(v.x * dv, v.y * dv);
  }
}

// rowptr + fold rowptr into shard bases (cb = rowptr[d] + local base) in place
__global__ __launch_bounds__(256) void k_scan3(const int* __restrict__ cnt_in,
                                               const int* __restrict__ partial,
                                               int* __restrict__ rowptr,
                                               int* __restrict__ cb) {
  __shared__ int sm[256];
  __shared__ int blkoff;
  int i = blockIdx.x * 256 + threadIdx.x;
  int t = threadIdx.x;

  sm[t] = (t < blockIdx.x && t < NB) ? partial[t] : 0;
  __syncthreads();
#pragma unroll
  for (int off = 128; off > 0; off >>= 1) {
    if (t < off) sm[t] += sm[t + off];
    __syncthreads();
  }
  if (t == 0) blkoff = sm[0];
  __syncthreads();

  int v = (i < N) ? cnt_in[i] : 0;
  sm[t] = v;
  __syncthreads();
#pragma unroll
  for (int off = 1; off < 256; off <<= 1) {
    int u = (t >= off) ? sm[t - off] : 0;
    __syncthreads();
    sm[t] += u;
    __syncthreads();
  }
  int excl = sm[t] - v + blkoff;
  if (i < N) {
    rowptr[i] = excl;
#pragma unroll
    for (int k = 0; k < KSH; ++k) cb[(size_t)k * N + i] += excl;
  }
  if (i == N) rowptr[N] = E;
}

// place edges into CSR order; single L2-resident gather: slot = cb[k][d] + pos[e]
__global__ __launch_bounds__(256) void k_build_csr(const int* __restrict__ src,
                                                   const int* __restrict__ dst,
                                                   const float* __restrict__ ew,
                                                   const int* __restrict__ cb,
                                                   const int* __restrict__ pos,
                                                   int2* __restrict__ csr) {
  int e = blockIdx.x * 256 + threadIdx.x;
  if (e >= E) return;
  int s = src[e], d = dst[e];
  int k = s >> 13;
  int p = cb[(size_t)k * N + d] + pos[e];
  csr[p] = make_int2(s, __float_as_int(ew[e]));
}

// ---------------- aggregation core (bf16 scaled gather, fp32 accumulate) ----------------
// returns dinv[node] * ( bhs[node] + sum_e ew_e * bhs[src_e] )  per lane (2 dims)
__device__ __forceinline__ float2 agg_core(const unsigned* __restrict__ bp,
                                           const int2* __restrict__ csr,
                                           int node, int e, int end, float s) {
  unsigned hb = bp[(size_t)node * 64];
  float ax = blo(hb), ay = bhi(hb);

  if ((e & 1) && e < end) {
    int2 pe = csr[e];
    float w = __int_as_float(pe.y);
    unsigned b = bp[(size_t)pe.x * 64];
    ax = fmaf(blo(b), w, ax); ay = fmaf(bhi(b), w, ay);
    ++e;
  }
  for (; e + 8 <= end; e += 8) {
    int4 p0 = *(const int4*)(csr + e + 0);
    int4 p1 = *(const int4*)(csr + e + 2);
    int4 p2 = *(const int4*)(csr + e + 4);
    int4 p3 = *(const int4*)(csr + e + 6);
    unsigned b0 = bp[(size_t)p0.x * 64];
    unsigned b1 = bp[(size_t)p0.z * 64];
    unsigned b2 = bp[(size_t)p1.x * 64];
    unsigned b3 = bp[(size_t)p1.z * 64];
    unsigned b4 = bp[(size_t)p2.x * 64];
    unsigned b5 = bp[(size_t)p2.z * 64];
    unsigned b6 = bp[(size_t)p3.x * 64];
    unsigned b7 = bp[(size_t)p3.z * 64];
    float w0 = __int_as_float(p0.y), w1 = __int_as_float(p0.w);
    float w2 = __int_as_float(p1.y), w3 = __int_as_float(p1.w);
    float w4 = __int_as_float(p2.y), w5 = __int_as_float(p2.w);
    float w6 = __int_as_float(p3.y), w7 = __int_as_float(p3.w);
    ax = fmaf(blo(b0), w0, ax); ay = fmaf(bhi(b0), w0, ay);
    ax = fmaf(blo(b1), w1, ax); ay = fmaf(bhi(b1), w1, ay);
    ax = fmaf(blo(b2), w2, ax); ay = fmaf(bhi(b2), w2, ay);
    ax = fmaf(blo(b3), w3, ax); ay = fmaf(bhi(b3), w3, ay);
    ax = fmaf(blo(b4), w4, ax); ay = fmaf(bhi(b4), w4, ay);
    ax = fmaf(blo(b5), w5, ax); ay = fmaf(bhi(b5), w5, ay);
    ax = fmaf(blo(b6), w6, ax); ay = fmaf(bhi(b6), w6, ay);
    ax = fmaf(blo(b7), w7, ax); ay = fmaf(bhi(b7), w7, ay);
  }
  for (; e + 2 <= end; e += 2) {
    int4 p0 = *(const int4*)(csr + e);
    unsigned b0 = bp[(size_t)p0.x * 64];
    unsigned b1 = bp[(size_t)p0.z * 64];
    float w0 = __int_as_float(p0.y), w1 = __int_as_float(p0.w);
    ax = fmaf(blo(b0), w0, ax); ay = fmaf(bhi(b0), w0, ay);
    ax = fmaf(blo(b1), w1, ax); ay = fmaf(bhi(b1), w1, ay);
  }
  if (e < end) {
    int2 pe = csr[e];
    float w = __int_as_float(pe.y);
    unsigned b = bp[(size_t)pe.x * 64];
    ax = fmaf(blo(b), w, ax); ay = fmaf(bhi(b), w, ay);
  }
  float2 r; r.x = ax * s; r.y = ay * s;
  return r;
}

// layers 1-2: bf16 output (GEMM A-operand)
__global__ __launch_bounds__(256) void k_agg_bf16(const unsigned* __restrict__ bhs,
                                                  const int* __restrict__ rowptr,
                                                  const int2* __restrict__ csr,
                                                  const float* __restrict__ dinv,
                                                  unsigned* __restrict__ outb) {
  int node = blockIdx.x * 4 + (threadIdx.x >> 6);
  if (node >= N) return;
  int lane = threadIdx.x & 63;
  float2 r = agg_core(bhs + lane, csr, node, rowptr[node], rowptr[node + 1], dinv[node]);
  outb[(size_t)node * 64 + lane] = pack_bf16(r.x, r.y);
}

// head layer: fp32 output
__global__ __launch_bounds__(256) void k_agg_f32(const unsigned* __restrict__ bhs,
                                                 const int* __restrict__ rowptr,
                                                 const int2* __restrict__ csr,
                                                 const float* __restrict__ dinv,
                                                 float* __restrict__ out) {
  int node = blockIdx.x * 4 + (threadIdx.x >> 6);
  if (node >= N) return;
  int lane = threadIdx.x & 63;
  float2 r = agg_core(bhs + lane, csr, node, rowptr[node], rowptr[node + 1], dinv[node]);
  *(float2*)(out + (size_t)node * D + lane * 2) = r;
}

// ---------------- GEMM: bhs_next = bf16( relu(A@W + b) * dinv )  (A in packed bf16) ----------------
__global__ __launch_bounds__(256) void k_gemm_relu_bf16(const unsigned* __restrict__ Ab,
                                                        const float* __restrict__ W,
                                                        const float* __restrict__ bias,
                                                        const float* __restrict__ dinv,
                                                        unsigned* __restrict__ outb) {
  __shared__ __align__(16) float Wl[128][128];
  __shared__ __align__(16) float Al[32][128];
  const int tid = threadIdx.x;

  {
    const float4* W4 = (const float4*)W;
    float4* Wl4 = (float4*)&Wl[0][0];
#pragma unroll
    for (int i = 0; i < 16; ++i) Wl4[tid + i * 256] = W4[tid + i * 256];
  }
  const int row0 = blockIdx.x * 32;
  {  // A tile: 32 rows x 64 uints = 512 uint4, unpack bf16 -> fp32 LDS
#pragma unroll
    for (int i = 0; i < 2; ++i) {
      int idx = tid + i * 256;
      int r = idx >> 4, c4 = idx & 15;
      uint4 v = make_uint4(0u, 0u, 0u, 0u);
      if (row0 + r < N) v = *(const uint4*)&Ab[(size_t)(row0 + r) * 64 + c4 * 4];
      float* dp = &Al[r][c4 * 8];
      dp[0] = blo(v.x); dp[1] = bhi(v.x);
      dp[2] = blo(v.y); dp[3] = bhi(v.y);
      dp[4] = blo(v.z); dp[5] = bhi(v.z);
      dp[6] = blo(v.w); dp[7] = bhi(v.w);
    }
  }
  __syncthreads();

  const int c0 = (tid & 31) * 4;
  const int r0 = (tid >> 5) * 4;
  float acc[4][4] = {};
  for (int k4 = 0; k4 < 32; ++k4) {
    float4 a[4];
#pragma unroll
    for (int r = 0; r < 4; ++r) a[r] = *(const float4*)&Al[r0 + r][k4 * 4];
    float4 w[4];
#pragma unroll
    for (int kk = 0; kk < 4; ++kk) w[kk] = *(const float4*)&Wl[k4 * 4 + kk][c0];
#pragma unroll
    for (int r = 0; r < 4; ++r) {
      float av0 = a[r].x, av1 = a[r].y, av2 = a[r].z, av3 = a[r].w;
#pragma unroll
      for (int cc = 0; cc < 4; ++cc) {
        float wv0 = (&w[0].x)[cc], wv1 = (&w[1].x)[cc], wv2 = (&w[2].x)[cc], wv3 = (&w[3].x)[cc];
        float v = acc[r][cc];
        v = fmaf(av0, wv0, v);
        v = fmaf(av1, wv1, v);
        v = fmaf(av2, wv2, v);
        v = fmaf(av3, wv3, v);
        acc[r][cc] = v;
      }
    }
  }
  float4 b = *(const float4*)&bias[c0];
#pragma unroll
  for (int r = 0; r < 4; ++r) {
    int row = row0 + r0 + r;
    if (row < N) {
      float dv = dinv[row];
      float v0 = fmaxf(acc[r][0] + b.x, 0.f) * dv;
      float v1 = fmaxf(acc[r][1] + b.y, 0.f) * dv;
      float v2 = fmaxf(acc[r][2] + b.z, 0.f) * dv;
      float v3 = fmaxf(acc[r][3] + b.w, 0.f) * dv;
      uint2 u;
      u.x = pack_bf16(v0, v1);
      u.y = pack_bf16(v2, v3);
      *(uint2*)&outb[(size_t)row * 64 + (c0 >> 1)] = u;
    }
  }
}

// heads: cols 0-63 -> mu, cols 64-127 -> std (fp32 A, fp32 out)
__global__ __launch_bounds__(256) void k_gemm_dual(const float* __restrict__ A,
                                                   const float* __restrict__ Wmu,
                                                   const float* __restrict__ Wstd,
                                                   const float* __restrict__ bmu,
                                                   const float* __restrict__ bstd,
                                                   float* __restrict__ out) {
  __shared__ __align__(16) float Wl[128][128];
  __shared__ __align__(16) float Al[32][128];
  const int tid = threadIdx.x;

  {
    const float4* Wm4 = (const float4*)Wmu;
    const float4* Ws4 = (const float4*)Wstd;
#pragma unroll
    for (int i = 0; i < 8; ++i) {
      int idx = tid + i * 256;
      int k = idx >> 4;
      int c4 = idx & 15;
      *(float4*)&Wl[k][c4 * 4] = Wm4[idx];
      *(float4*)&Wl[k][64 + c4 * 4] = Ws4[idx];
    }
  }
  const int row0 = blockIdx.x * 32;
  {
    const float4* A4 = (const float4*)(A + (size_t)row0 * D);
    float4* Al4 = (float4*)&Al[0][0];
#pragma unroll
    for (int i = 0; i < 4; ++i) {
      int idx = tid + i * 256;
      int r = idx >> 5;
      float4 v = make_float4(0.f, 0.f, 0.f, 0.f);
      if (row0 + r < N) v = A4[idx];
      Al4[idx] = v;
    }
  }
  __syncthreads();

  const int c0 = (tid & 31) * 4;
  const int r0 = (tid >> 5) * 4;
  float acc[4][4] = {};
  for (int k4 = 0; k4 < 32; ++k4) {
    float4 a[4];
#pragma unroll
    for (int r = 0; r < 4; ++r) a[r] = *(const float4*)&Al[r0 + r][k4 * 4];
    float4 w[4];
#pragma unroll
    for (int kk = 0; kk < 4; ++kk) w[kk] = *(const float4*)&Wl[k4 * 4 + kk][c0];
#pragma unroll
    for (int r = 0; r < 4; ++r) {
      float av0 = a[r].x, av1 = a[r].y, av2 = a[r].z, av3 = a[r].w;
#pragma unroll
      for (int cc = 0; cc < 4; ++cc) {
        float wv0 = (&w[0].x)[cc], wv1 = (&w[1].x)[cc], wv2 = (&w[2].x)[cc], wv3 = (&w[3].x)[cc];
        float v = acc[r][cc];
        v = fmaf(av0, wv0, v);
        v = fmaf(av1, wv1, v);
        v = fmaf(av2, wv2, v);
        v = fmaf(av3, wv3, v);
        acc[r][cc] = v;
      }
    }
  }
  const bool is_mu = (c0 < DO);
  const int cc0 = is_mu ? c0 : (c0 - DO);
  const float* bsel = is_mu ? bmu : bstd;
  float4 b = *(const float4*)&bsel[cc0];
  float* base = is_mu ? out : (out + (size_t)N * DO);
#pragma unroll
  for (int r = 0; r < 4; ++r) {
    int row = row0 + r0 + r;
    if (row < N) {
      float4 v;
      v.x = acc[r][0] + b.x; v.y = acc[r][1] + b.y;
      v.z = acc[r][2] + b.z; v.w = acc[r][3] + b.w;
      *(float4*)&base[(size_t)row * DO + cc0] = v;
    }
  }
}

// ---------------- launcher ----------------

static inline char* align256(char* p) {
  return (char*)(((uintptr_t)p + 255) & ~(uintptr_t)255);
}

extern "C" void kernel_launch(void* const* d_in, const int* in_sizes, int n_in,
                              void* d_out, int out_size, void* d_ws, size_t ws_size,
                              hipStream_t stream) {
  const float* x    = (const float*)d_in[0];
  const int*   ei   = (const int*)d_in[1];     // [2, E] int32
  const float* ew   = (const float*)d_in[2];
  const float* W1   = (const float*)d_in[3];
  const float* b1   = (const float*)d_in[4];
  const float* W2   = (const float*)d_in[5];
  const float* b2   = (const float*)d_in[6];
  const float* Wmu  = (const float*)d_in[7];
  const float* bmu  = (const float*)d_in[8];
  const float* Wstd = (const float*)d_in[9];
  const float* bstd = (const float*)d_in[10];
  float* out = (float*)d_out;

  const int* srcI = ei;
  const int* dstI = ei + E;

  char* p = (char*)d_ws;
  float*    dinv    = (float*)p;     p = align256(p + (size_t)N * 4);
  int*      rowptr  = (int*)p;       p = align256(p + (size_t)(N + 1) * 4);
  int*      cnt     = (int*)p;       p = align256(p + (size_t)N * 4);
  int*      partial = (int*)p;       p = align256(p + (size_t)256 * 4);
  int2*     csr     = (int2*)p;      p = align256(p + (size_t)E * 8);      // 6.4 MB
  float*    buf0    = (float*)p;     p = align256(p + (size_t)N * D * 4);  // 25.6 MB
  unsigned* bhs     = (unsigned*)p;  p = align256(p + (size_t)N * 64 * 4); // 12.8 MB
  unsigned* bfA     = (unsigned*)p;  p = align256(p + (size_t)N * 64 * 4); // 12.8 MB
  // transient aliases inside buf0 (all dead before first write of buf0 by k_agg_f32)
  int* pos = (int*)buf0;                                                    // E*4   = 3.2 MB
  unsigned long long* packed_sh =
      (unsigned long long*)((char*)buf0 + (4 << 20));                       // KSH*N*8 = 3.2 MB
  int* cb = (int*)((char*)buf0 + (12 << 20));                               // KSH*N*4 = 1.6 MB

  dim3 blk(256);
  const int gN1   = (N + 256) / 256;       // covers i == N in scan3
  const int gE    = (E + 255) / 256;
  const int gAgg  = (N + 3) / 4;
  const int gGemm = (N + 31) / 32;
  const int gCast = (N * 64 + 255) / 256;
  const int gZero = (KSH * N + 255) / 256;

  // CSR + norm precompute (once per call)
  k_zero<<<gZero, blk, 0, stream>>>(packed_sh);
  k_hist<<<gE, blk, 0, stream>>>(srcI, dstI, ew, packed_sh, pos);
  k_scan1<<<NB, blk, 0, stream>>>(packed_sh, dinv, cnt, cb, partial);
  k_cast<<<gCast, blk, 0, stream>>>(x, dinv, bhs);
  k_scan3<<<gN1, blk, 0, stream>>>(cnt, partial, rowptr, cb);
  k_build_csr<<<gE, blk, 0, stream>>>(srcI, dstI, ew, cb, pos, csr);

  // layer 1: h1 = relu(A(x) @ W1 + b1)
  k_agg_bf16<<<gAgg, blk, 0, stream>>>(bhs, rowptr, csr, dinv, bfA);
  k_gemm_relu_bf16<<<gGemm, blk, 0, stream>>>(bfA, W1, b1, dinv, bhs);

  // layer 2: h2 = relu(A(h1) @ W2 + b2)
  k_agg_bf16<<<gAgg, blk, 0, stream>>>(bhs, rowptr, csr, dinv, bfA);
  k_gemm_relu_bf16<<<gGemm, blk, 0, stream>>>(bfA, W2, b2, dinv, bhs);

  // heads: one shared aggregation (fp32 out), two output projections
  k_agg_f32<<<gAgg, blk, 0, stream>>>(bhs, rowptr, csr, dinv, buf0);
  k_gemm_dual<<<gGemm, blk, 0, stream>>>(buf0, Wmu, Wstd, bmu, bstd, out);
}

// Round 10
// 274.153 us; speedup vs baseline: 1.0134x; 1.0134x over previous
//
#include <hip/hip_runtime.h>
#include <math.h>

static constexpr int N = 50000;
static constexpr int E = 800000;
static constexpr int D = 128;      // D_IN = D_HID
static constexpr int DO = 64;      // D_OUT
static constexpr int NB = (N + 255) / 256;   // 196 scan blocks

// ---- bf16 helpers ----
__device__ __forceinline__ unsigned pack_bf16(float a, float b) {
  unsigned ua = __float_as_uint(a), ub = __float_as_uint(b);
  ua = (ua + 0x7FFFu + ((ua >> 16) & 1u)) >> 16;
  ub = (ub + 0x7FFFu + ((ub >> 16) & 1u)) >> 16;
  return ua | (ub << 16);
}
__device__ __forceinline__ float blo(unsigned u) { return __uint_as_float(u << 16); }
__device__ __forceinline__ float bhi(unsigned u) { return __uint_as_float(u & 0xFFFF0000u); }

// ---------------- zero per-dst counters ----------------
__global__ __launch_bounds__(256) void k_zero(int* __restrict__ cnt) {
  int i = blockIdx.x * 256 + threadIdx.x;
  if (i < N) cnt[i] = 0;
}

// ---------------- count histogram (u32 atomic with return -> slot) ----------------
__global__ __launch_bounds__(256) void k_hist(const int* __restrict__ dst,
                                              int* __restrict__ cnt,
                                              int* __restrict__ pos) {
  int e = blockIdx.x * 256 + threadIdx.x;
  if (e < E) {
    pos[e] = __hip_atomic_fetch_add(&cnt[dst[e]], 1, __ATOMIC_RELAXED, __HIP_MEMORY_SCOPE_AGENT);
  }
}

// block sums of cnt
__global__ __launch_bounds__(256) void k_scan1(const int* __restrict__ cnt,
                                               int* __restrict__ partial) {
  __shared__ int sm[256];
  int i = blockIdx.x * 256 + threadIdx.x;
  int t = threadIdx.x;
  sm[t] = (i < N) ? cnt[i] : 0;
  __syncthreads();
#pragma unroll
  for (int off = 128; off > 0; off >>= 1) {
    if (t < off) sm[t] += sm[t + off];
    __syncthreads();
  }
  if (t == 0) partial[blockIdx.x] = sm[0];
}

// rowptr = exclusive scan of cnt (block-offset reduction fused)
__global__ __launch_bounds__(256) void k_scan3(const int* __restrict__ cnt_in,
                                               const int* __restrict__ partial,
                                               int* __restrict__ rowptr) {
  __shared__ int sm[256];
  __shared__ int blkoff;
  int i = blockIdx.x * 256 + threadIdx.x;
  int t = threadIdx.x;

  sm[t] = (t < blockIdx.x && t < NB) ? partial[t] : 0;
  __syncthreads();
#pragma unroll
  for (int off = 128; off > 0; off >>= 1) {
    if (t < off) sm[t] += sm[t + off];
    __syncthreads();
  }
  if (t == 0) blkoff = sm[0];
  __syncthreads();

  int v = (i < N) ? cnt_in[i] : 0;
  sm[t] = v;
  __syncthreads();
#pragma unroll
  for (int off = 1; off < 256; off <<= 1) {
    int u = (t >= off) ? sm[t - off] : 0;
    __syncthreads();
    sm[t] += u;
    __syncthreads();
  }
  int excl = sm[t] - v + blkoff;
  if (i < N) rowptr[i] = excl;
  if (i == N) rowptr[N] = E;
}

// place edges into CSR order: slot = rowptr[dst] + pos[e]; store (src, raw ew)
__global__ __launch_bounds__(256) void k_build_csr(const int* __restrict__ src,
                                                   const int* __restrict__ dst,
                                                   const float* __restrict__ ew,
                                                   const int* __restrict__ rowptr,
                                                   const int* __restrict__ pos,
                                                   int2* __restrict__ csr) {
  int e = blockIdx.x * 256 + threadIdx.x;
  if (e >= E) return;
  int s = src[e], d = dst[e];
  int p = rowptr[d] + pos[e];
  csr[p] = make_int2(s, __float_as_int(ew[e]));
}

// ---------------- deg (from CSR) -> dinv -> cast x to scaled bf16, one wave/node ----------------
__global__ __launch_bounds__(256) void k_degcast(const float* __restrict__ x,
                                                 const int* __restrict__ rowptr,
                                                 const int2* __restrict__ csr,
                                                 float* __restrict__ dinv,
                                                 unsigned* __restrict__ bhs) {
  int node = blockIdx.x * 4 + (threadIdx.x >> 6);
  if (node >= N) return;
  int lane = threadIdx.x & 63;

  int beg = rowptr[node], end = rowptr[node + 1];
  float sum = 0.f;
  for (int j = beg + lane; j < end; j += 64) sum += __int_as_float(csr[j].y);
#pragma unroll
  for (int off = 1; off < 64; off <<= 1) sum += __shfl_xor(sum, off, 64);

  float dv = 1.0f / sqrtf(1.0f + sum);
  if (lane == 0) dinv[node] = dv;

  float2 v = ((const float2*)x)[(size_t)node * 64 + lane];
  bhs[(size_t)node * 64 + lane] = pack_bf16(v.x * dv, v.y * dv);
}

// ---------------- aggregation core (bf16 scaled gather, fp32 accumulate) ----------------
// returns dinv[node] * ( bhs[node] + sum_e ew_e * bhs[src_e] )  per lane (2 dims)
__device__ __forceinline__ float2 agg_core(const unsigned* __restrict__ bp,
                                           const int2* __restrict__ csr,
                                           int node, int e, int end, float s) {
  unsigned hb = bp[(size_t)node * 64];
  float ax = blo(hb), ay = bhi(hb);

  if ((e & 1) && e < end) {
    int2 pe = csr[e];
    float w = __int_as_float(pe.y);
    unsigned b = bp[(size_t)pe.x * 64];
    ax = fmaf(blo(b), w, ax); ay = fmaf(bhi(b), w, ay);
    ++e;
  }
  for (; e + 8 <= end; e += 8) {
    int4 p0 = *(const int4*)(csr + e + 0);
    int4 p1 = *(const int4*)(csr + e + 2);
    int4 p2 = *(const int4*)(csr + e + 4);
    int4 p3 = *(const int4*)(csr + e + 6);
    unsigned b0 = bp[(size_t)p0.x * 64];
    unsigned b1 = bp[(size_t)p0.z * 64];
    unsigned b2 = bp[(size_t)p1.x * 64];
    unsigned b3 = bp[(size_t)p1.z * 64];
    unsigned b4 = bp[(size_t)p2.x * 64];
    unsigned b5 = bp[(size_t)p2.z * 64];
    unsigned b6 = bp[(size_t)p3.x * 64];
    unsigned b7 = bp[(size_t)p3.z * 64];
    float w0 = __int_as_float(p0.y), w1 = __int_as_float(p0.w);
    float w2 = __int_as_float(p1.y), w3 = __int_as_float(p1.w);
    float w4 = __int_as_float(p2.y), w5 = __int_as_float(p2.w);
    float w6 = __int_as_float(p3.y), w7 = __int_as_float(p3.w);
    ax = fmaf(blo(b0), w0, ax); ay = fmaf(bhi(b0), w0, ay);
    ax = fmaf(blo(b1), w1, ax); ay = fmaf(bhi(b1), w1, ay);
    ax = fmaf(blo(b2), w2, ax); ay = fmaf(bhi(b2), w2, ay);
    ax = fmaf(blo(b3), w3, ax); ay = fmaf(bhi(b3), w3, ay);
    ax = fmaf(blo(b4), w4, ax); ay = fmaf(bhi(b4), w4, ay);
    ax = fmaf(blo(b5), w5, ax); ay = fmaf(bhi(b5), w5, ay);
    ax = fmaf(blo(b6), w6, ax); ay = fmaf(bhi(b6), w6, ay);
    ax = fmaf(blo(b7), w7, ax); ay = fmaf(bhi(b7), w7, ay);
  }
  for (; e + 2 <= end; e += 2) {
    int4 p0 = *(const int4*)(csr + e);
    unsigned b0 = bp[(size_t)p0.x * 64];
    unsigned b1 = bp[(size_t)p0.z * 64];
    float w0 = __int_as_float(p0.y), w1 = __int_as_float(p0.w);
    ax = fmaf(blo(b0), w0, ax); ay = fmaf(bhi(b0), w0, ay);
    ax = fmaf(blo(b1), w1, ax); ay = fmaf(bhi(b1), w1, ay);
  }
  if (e < end) {
    int2 pe = csr[e];
    float w = __int_as_float(pe.y);
    unsigned b = bp[(size_t)pe.x * 64];
    ax = fmaf(blo(b), w, ax); ay = fmaf(bhi(b), w, ay);
  }
  float2 r; r.x = ax * s; r.y = ay * s;
  return r;
}

// all layers: bf16 output (GEMM A-operand)
__global__ __launch_bounds__(256) void k_agg_bf16(const unsigned* __restrict__ bhs,
                                                  const int* __restrict__ rowptr,
                                                  const int2* __restrict__ csr,
                                                  const float* __restrict__ dinv,
                                                  unsigned* __restrict__ outb) {
  int node = blockIdx.x * 4 + (threadIdx.x >> 6);
  if (node >= N) return;
  int lane = threadIdx.x & 63;
  float2 r = agg_core(bhs + lane, csr, node, rowptr[node], rowptr[node + 1], dinv[node]);
  outb[(size_t)node * 64 + lane] = pack_bf16(r.x, r.y);
}

// ---------------- GEMM: bhs_next = bf16( relu(A@W + b) * dinv )  (A packed bf16) ----------------
__global__ __launch_bounds__(256) void k_gemm_relu_bf16(const unsigned* __restrict__ Ab,
                                                        const float* __restrict__ W,
                                                        const float* __restrict__ bias,
                                                        const float* __restrict__ dinv,
                                                        unsigned* __restrict__ outb) {
  __shared__ __align__(16) float Wl[128][128];
  __shared__ __align__(16) float Al[32][128];
  const int tid = threadIdx.x;

  {
    const float4* W4 = (const float4*)W;
    float4* Wl4 = (float4*)&Wl[0][0];
#pragma unroll
    for (int i = 0; i < 16; ++i) Wl4[tid + i * 256] = W4[tid + i * 256];
  }
  const int row0 = blockIdx.x * 32;
  {  // A tile: 32 rows x 64 uints = 512 uint4, unpack bf16 -> fp32 LDS
#pragma unroll
    for (int i = 0; i < 2; ++i) {
      int idx = tid + i * 256;
      int r = idx >> 4, c4 = idx & 15;
      uint4 v = make_uint4(0u, 0u, 0u, 0u);
      if (row0 + r < N) v = *(const uint4*)&Ab[(size_t)(row0 + r) * 64 + c4 * 4];
      float* dp = &Al[r][c4 * 8];
      dp[0] = blo(v.x); dp[1] = bhi(v.x);
      dp[2] = blo(v.y); dp[3] = bhi(v.y);
      dp[4] = blo(v.z); dp[5] = bhi(v.z);
      dp[6] = blo(v.w); dp[7] = bhi(v.w);
    }
  }
  __syncthreads();

  const int c0 = (tid & 31) * 4;
  const int r0 = (tid >> 5) * 4;
  float acc[4][4] = {};
  for (int k4 = 0; k4 < 32; ++k4) {
    float4 a[4];
#pragma unroll
    for (int r = 0; r < 4; ++r) a[r] = *(const float4*)&Al[r0 + r][k4 * 4];
    float4 w[4];
#pragma unroll
    for (int kk = 0; kk < 4; ++kk) w[kk] = *(const float4*)&Wl[k4 * 4 + kk][c0];
#pragma unroll
    for (int r = 0; r < 4; ++r) {
      float av0 = a[r].x, av1 = a[r].y, av2 = a[r].z, av3 = a[r].w;
#pragma unroll
      for (int cc = 0; cc < 4; ++cc) {
        float wv0 = (&w[0].x)[cc], wv1 = (&w[1].x)[cc], wv2 = (&w[2].x)[cc], wv3 = (&w[3].x)[cc];
        float v = acc[r][cc];
        v = fmaf(av0, wv0, v);
        v = fmaf(av1, wv1, v);
        v = fmaf(av2, wv2, v);
        v = fmaf(av3, wv3, v);
        acc[r][cc] = v;
      }
    }
  }
  float4 b = *(const float4*)&bias[c0];
#pragma unroll
  for (int r = 0; r < 4; ++r) {
    int row = row0 + r0 + r;
    if (row < N) {
      float dv = dinv[row];
      float v0 = fmaxf(acc[r][0] + b.x, 0.f) * dv;
      float v1 = fmaxf(acc[r][1] + b.y, 0.f) * dv;
      float v2 = fmaxf(acc[r][2] + b.z, 0.f) * dv;
      float v3 = fmaxf(acc[r][3] + b.w, 0.f) * dv;
      uint2 u;
      u.x = pack_bf16(v0, v1);
      u.y = pack_bf16(v2, v3);
      *(uint2*)&outb[(size_t)row * 64 + (c0 >> 1)] = u;
    }
  }
}

// heads: A packed bf16; cols 0-63 -> mu, cols 64-127 -> std (fp32 out)
__global__ __launch_bounds__(256) void k_gemm_dual_bf16(const unsigned* __restrict__ Ab,
                                                        const float* __restrict__ Wmu,
                                                        const float* __restrict__ Wstd,
                                                        const float* __restrict__ bmu,
                                                        const float* __restrict__ bstd,
                                                        float* __restrict__ out) {
  __shared__ __align__(16) float Wl[128][128];
  __shared__ __align__(16) float Al[32][128];
  const int tid = threadIdx.x;

  {
    const float4* Wm4 = (const float4*)Wmu;
    const float4* Ws4 = (const float4*)Wstd;
#pragma unroll
    for (int i = 0; i < 8; ++i) {
      int idx = tid + i * 256;
      int k = idx >> 4;
      int c4 = idx & 15;
      *(float4*)&Wl[k][c4 * 4] = Wm4[idx];
      *(float4*)&Wl[k][64 + c4 * 4] = Ws4[idx];
    }
  }
  const int row0 = blockIdx.x * 32;
  {  // A tile: unpack bf16 -> fp32 LDS
#pragma unroll
    for (int i = 0; i < 2; ++i) {
      int idx = tid + i * 256;
      int r = idx >> 4, c4 = idx & 15;
      uint4 v = make_uint4(0u, 0u, 0u, 0u);
      if (row0 + r < N) v = *(const uint4*)&Ab[(size_t)(row0 + r) * 64 + c4 * 4];
      float* dp = &Al[r][c4 * 8];
      dp[0] = blo(v.x); dp[1] = bhi(v.x);
      dp[2] = blo(v.y); dp[3] = bhi(v.y);
      dp[4] = blo(v.z); dp[5] = bhi(v.z);
      dp[6] = blo(v.w); dp[7] = bhi(v.w);
    }
  }
  __syncthreads();

  const int c0 = (tid & 31) * 4;
  const int r0 = (tid >> 5) * 4;
  float acc[4][4] = {};
  for (int k4 = 0; k4 < 32; ++k4) {
    float4 a[4];
#pragma unroll
    for (int r = 0; r < 4; ++r) a[r] = *(const float4*)&Al[r0 + r][k4 * 4];
    float4 w[4];
#pragma unroll
    for (int kk = 0; kk < 4; ++kk) w[kk] = *(const float4*)&Wl[k4 * 4 + kk][c0];
#pragma unroll
    for (int r = 0; r < 4; ++r) {
      float av0 = a[r].x, av1 = a[r].y, av2 = a[r].z, av3 = a[r].w;
#pragma unroll
      for (int cc = 0; cc < 4; ++cc) {
        float wv0 = (&w[0].x)[cc], wv1 = (&w[1].x)[cc], wv2 = (&w[2].x)[cc], wv3 = (&w[3].x)[cc];
        float v = acc[r][cc];
        v = fmaf(av0, wv0, v);
        v = fmaf(av1, wv1, v);
        v = fmaf(av2, wv2, v);
        v = fmaf(av3, wv3, v);
        acc[r][cc] = v;
      }
    }
  }
  const bool is_mu = (c0 < DO);
  const int cc0 = is_mu ? c0 : (c0 - DO);
  const float* bsel = is_mu ? bmu : bstd;
  float4 b = *(const float4*)&bsel[cc0];
  float* base = is_mu ? out : (out + (size_t)N * DO);
#pragma unroll
  for (int r = 0; r < 4; ++r) {
    int row = row0 + r0 + r;
    if (row < N) {
      float4 v;
      v.x = acc[r][0] + b.x; v.y = acc[r][1] + b.y;
      v.z = acc[r][2] + b.z; v.w = acc[r][3] + b.w;
      *(float4*)&base[(size_t)row * DO + cc0] = v;
    }
  }
}

// ---------------- launcher ----------------

static inline char* align256(char* p) {
  return (char*)(((uintptr_t)p + 255) & ~(uintptr_t)255);
}

extern "C" void kernel_launch(void* const* d_in, const int* in_sizes, int n_in,
                              void* d_out, int out_size, void* d_ws, size_t ws_size,
                              hipStream_t stream) {
  const float* x    = (const float*)d_in[0];
  const int*   ei   = (const int*)d_in[1];     // [2, E] int32
  const float* ew   = (const float*)d_in[2];
  const float* W1   = (const float*)d_in[3];
  const float* b1   = (const float*)d_in[4];
  const float* W2   = (const float*)d_in[5];
  const float* b2   = (const float*)d_in[6];
  const float* Wmu  = (const float*)d_in[7];
  const float* bmu  = (const float*)d_in[8];
  const float* Wstd = (const float*)d_in[9];
  const float* bstd = (const float*)d_in[10];
  float* out = (float*)d_out;

  const int* srcI = ei;
  const int* dstI = ei + E;

  char* p = (char*)d_ws;
  float*    dinv    = (float*)p;     p = align256(p + (size_t)N * 4);
  int*      rowptr  = (int*)p;       p = align256(p + (size_t)(N + 1) * 4);
  int*      cnt     = (int*)p;       p = align256(p + (size_t)N * 4);
  int*      partial = (int*)p;       p = align256(p + (size_t)256 * 4);
  int*      pos     = (int*)p;       p = align256(p + (size_t)E * 4);      // 3.2 MB
  int2*     csr     = (int2*)p;      p = align256(p + (size_t)E * 8);      // 6.4 MB
  unsigned* bhs     = (unsigned*)p;  p = align256(p + (size_t)N * 64 * 4); // 12.8 MB
  unsigned* bfA     = (unsigned*)p;  p = align256(p + (size_t)N * 64 * 4); // 12.8 MB

  dim3 blk(256);
  const int gN    = (N + 255) / 256;
  const int gN1   = (N + 256) / 256;       // covers i == N in scan3
  const int gE    = (E + 255) / 256;
  const int gAgg  = (N + 3) / 4;
  const int gGemm = (N + 31) / 32;

  // CSR + norm precompute (once per call)
  k_zero<<<gN, blk, 0, stream>>>(cnt);
  k_hist<<<gE, blk, 0, stream>>>(dstI, cnt, pos);
  k_scan1<<<NB, blk, 0, stream>>>(cnt, partial);
  k_scan3<<<gN1, blk, 0, stream>>>(cnt, partial, rowptr);
  k_build_csr<<<gE, blk, 0, stream>>>(srcI, dstI, ew, rowptr, pos, csr);
  k_degcast<<<gAgg, blk, 0, stream>>>(x, rowptr, csr, dinv, bhs);

  // layer 1: h1 = relu(A(x) @ W1 + b1)
  k_agg_bf16<<<gAgg, blk, 0, stream>>>(bhs, rowptr, csr, dinv, bfA);
  k_gemm_relu_bf16<<<gGemm, blk, 0, stream>>>(bfA, W1, b1, dinv, bhs);

  // layer 2: h2 = relu(A(h1) @ W2 + b2)
  k_agg_bf16<<<gAgg, blk, 0, stream>>>(bhs, rowptr, csr, dinv, bfA);
  k_gemm_relu_bf16<<<gGemm, blk, 0, stream>>>(bfA, W2, b2, dinv, bhs);

  // heads: one shared aggregation (bf16 out), dual projection
  k_agg_bf16<<<gAgg, blk, 0, stream>>>(bhs, rowptr, csr, dinv, bfA);
  k_gemm_dual_bf16<<<gGemm, blk, 0, stream>>>(bfA, Wmu, Wstd, bmu, bstd, out);
}

// Round 11
// 260.507 us; speedup vs baseline: 1.0665x; 1.0524x over previous
//
#include <hip/hip_runtime.h>
#include <math.h>

static constexpr int N = 50000;
static constexpr int E = 800000;
static constexpr int D = 128;      // D_IN = D_HID
static constexpr int DO = 64;      // D_OUT
static constexpr int CAP = 64;     // ELL row capacity (Poisson(16); P(deg>64) ~ 1e-26)

// ---- bf16 helpers ----
__device__ __forceinline__ unsigned pack_bf16(float a, float b) {
  unsigned ua = __float_as_uint(a), ub = __float_as_uint(b);
  ua = (ua + 0x7FFFu + ((ua >> 16) & 1u)) >> 16;
  ub = (ub + 0x7FFFu + ((ub >> 16) & 1u)) >> 16;
  return ua | (ub << 16);
}
__device__ __forceinline__ float blo(unsigned u) { return __uint_as_float(u << 16); }
__device__ __forceinline__ float bhi(unsigned u) { return __uint_as_float(u & 0xFFFF0000u); }

// ---------------- zero per-dst counters ----------------
__global__ __launch_bounds__(256) void k_zero(int* __restrict__ cnt) {
  int i = blockIdx.x * 256 + threadIdx.x;
  if (i < N) cnt[i] = 0;
}

// ---------------- single-pass ELL build: slot = atomic count, row = dst*CAP ----------------
__global__ __launch_bounds__(256) void k_build_ell(const int* __restrict__ src,
                                                   const int* __restrict__ dst,
                                                   const float* __restrict__ ew,
                                                   int* __restrict__ cnt,
                                                   int2* __restrict__ ell) {
  int e = blockIdx.x * 256 + threadIdx.x;
  if (e >= E) return;
  int s = src[e], d = dst[e];
  int pos = __hip_atomic_fetch_add(&cnt[d], 1, __ATOMIC_RELAXED, __HIP_MEMORY_SCOPE_AGENT);
  if (pos < CAP)   // statistically unreachable; guards memory safety
    ell[(size_t)d * CAP + pos] = make_int2(s, __float_as_int(ew[e]));
}

// ---------------- deg -> dinv -> cast x to scaled bf16, one wave/node ----------------
__global__ __launch_bounds__(256) void k_degcast(const float* __restrict__ x,
                                                 const int* __restrict__ cnt,
                                                 const int2* __restrict__ ell,
                                                 float* __restrict__ dinv,
                                                 unsigned* __restrict__ bhs) {
  int node = blockIdx.x * 4 + (threadIdx.x >> 6);
  if (node >= N) return;
  int lane = threadIdx.x & 63;

  int len = cnt[node];
  float sum = (lane < len) ? __int_as_float(ell[(size_t)node * CAP + lane].y) : 0.f;
#pragma unroll
  for (int off = 1; off < 64; off <<= 1) sum += __shfl_xor(sum, off, 64);

  float dv = 1.0f / sqrtf(1.0f + sum);
  if (lane == 0) dinv[node] = dv;

  float2 v = ((const float2*)x)[(size_t)node * 64 + lane];
  bhs[(size_t)node * 64 + lane] = pack_bf16(v.x * dv, v.y * dv);
}

// ---------------- aggregation core (bf16 scaled gather, fp32 accumulate) ----------------
// returns dinv[node] * ( bhs[node] + sum_e ew_e * bhs[src_e] )  per lane (2 dims)
// ELL rows are 512B-aligned: int4 loads need no peel.
__device__ __forceinline__ float2 agg_core(const unsigned* __restrict__ bp,
                                           const int2* __restrict__ ell,
                                           int node, int len, float s) {
  unsigned hb = bp[(size_t)node * 64];
  float ax = blo(hb), ay = bhi(hb);

  const int2* row = ell + (size_t)node * CAP;
  int e = 0;
  for (; e + 8 <= len; e += 8) {
    int4 p0 = *(const int4*)(row + e + 0);
    int4 p1 = *(const int4*)(row + e + 2);
    int4 p2 = *(const int4*)(row + e + 4);
    int4 p3 = *(const int4*)(row + e + 6);
    unsigned b0 = bp[(size_t)p0.x * 64];
    unsigned b1 = bp[(size_t)p0.z * 64];
    unsigned b2 = bp[(size_t)p1.x * 64];
    unsigned b3 = bp[(size_t)p1.z * 64];
    unsigned b4 = bp[(size_t)p2.x * 64];
    unsigned b5 = bp[(size_t)p2.z * 64];
    unsigned b6 = bp[(size_t)p3.x * 64];
    unsigned b7 = bp[(size_t)p3.z * 64];
    float w0 = __int_as_float(p0.y), w1 = __int_as_float(p0.w);
    float w2 = __int_as_float(p1.y), w3 = __int_as_float(p1.w);
    float w4 = __int_as_float(p2.y), w5 = __int_as_float(p2.w);
    float w6 = __int_as_float(p3.y), w7 = __int_as_float(p3.w);
    ax = fmaf(blo(b0), w0, ax); ay = fmaf(bhi(b0), w0, ay);
    ax = fmaf(blo(b1), w1, ax); ay = fmaf(bhi(b1), w1, ay);
    ax = fmaf(blo(b2), w2, ax); ay = fmaf(bhi(b2), w2, ay);
    ax = fmaf(blo(b3), w3, ax); ay = fmaf(bhi(b3), w3, ay);
    ax = fmaf(blo(b4), w4, ax); ay = fmaf(bhi(b4), w4, ay);
    ax = fmaf(blo(b5), w5, ax); ay = fmaf(bhi(b5), w5, ay);
    ax = fmaf(blo(b6), w6, ax); ay = fmaf(bhi(b6), w6, ay);
    ax = fmaf(blo(b7), w7, ax); ay = fmaf(bhi(b7), w7, ay);
  }
  for (; e + 2 <= len; e += 2) {
    int4 p0 = *(const int4*)(row + e);
    unsigned b0 = bp[(size_t)p0.x * 64];
    unsigned b1 = bp[(size_t)p0.z * 64];
    float w0 = __int_as_float(p0.y), w1 = __int_as_float(p0.w);
    ax = fmaf(blo(b0), w0, ax); ay = fmaf(bhi(b0), w0, ay);
    ax = fmaf(blo(b1), w1, ax); ay = fmaf(bhi(b1), w1, ay);
  }
  if (e < len) {
    int2 pe = row[e];
    float w = __int_as_float(pe.y);
    unsigned b = bp[(size_t)pe.x * 64];
    ax = fmaf(blo(b), w, ax); ay = fmaf(bhi(b), w, ay);
  }
  float2 r; r.x = ax * s; r.y = ay * s;
  return r;
}

// all layers: bf16 output (GEMM A-operand)
__global__ __launch_bounds__(256) void k_agg_bf16(const unsigned* __restrict__ bhs,
                                                  const int* __restrict__ cnt,
                                                  const int2* __restrict__ ell,
                                                  const float* __restrict__ dinv,
                                                  unsigned* __restrict__ outb) {
  int node = blockIdx.x * 4 + (threadIdx.x >> 6);
  if (node >= N) return;
  int lane = threadIdx.x & 63;
  float2 r = agg_core(bhs + lane, ell, node, cnt[node], dinv[node]);
  outb[(size_t)node * 64 + lane] = pack_bf16(r.x, r.y);
}

// ---------------- GEMM: bhs_next = bf16( relu(A@W + b) * dinv )  (A packed bf16) ----------------
__global__ __launch_bounds__(256) void k_gemm_relu_bf16(const unsigned* __restrict__ Ab,
                                                        const float* __restrict__ W,
                                                        const float* __restrict__ bias,
                                                        const float* __restrict__ dinv,
                                                        unsigned* __restrict__ outb) {
  __shared__ __align__(16) float Wl[128][128];
  __shared__ __align__(16) float Al[32][128];
  const int tid = threadIdx.x;

  {
    const float4* W4 = (const float4*)W;
    float4* Wl4 = (float4*)&Wl[0][0];
#pragma unroll
    for (int i = 0; i < 16; ++i) Wl4[tid + i * 256] = W4[tid + i * 256];
  }
  const int row0 = blockIdx.x * 32;
  {  // A tile: 32 rows x 64 uints = 512 uint4, unpack bf16 -> fp32 LDS
#pragma unroll
    for (int i = 0; i < 2; ++i) {
      int idx = tid + i * 256;
      int r = idx >> 4, c4 = idx & 15;
      uint4 v = make_uint4(0u, 0u, 0u, 0u);
      if (row0 + r < N) v = *(const uint4*)&Ab[(size_t)(row0 + r) * 64 + c4 * 4];
      float* dp = &Al[r][c4 * 8];
      dp[0] = blo(v.x); dp[1] = bhi(v.x);
      dp[2] = blo(v.y); dp[3] = bhi(v.y);
      dp[4] = blo(v.z); dp[5] = bhi(v.z);
      dp[6] = blo(v.w); dp[7] = bhi(v.w);
    }
  }
  __syncthreads();

  const int c0 = (tid & 31) * 4;
  const int r0 = (tid >> 5) * 4;
  float acc[4][4] = {};
  for (int k4 = 0; k4 < 32; ++k4) {
    float4 a[4];
#pragma unroll
    for (int r = 0; r < 4; ++r) a[r] = *(const float4*)&Al[r0 + r][k4 * 4];
    float4 w[4];
#pragma unroll
    for (int kk = 0; kk < 4; ++kk) w[kk] = *(const float4*)&Wl[k4 * 4 + kk][c0];
#pragma unroll
    for (int r = 0; r < 4; ++r) {
      float av0 = a[r].x, av1 = a[r].y, av2 = a[r].z, av3 = a[r].w;
#pragma unroll
      for (int cc = 0; cc < 4; ++cc) {
        float wv0 = (&w[0].x)[cc], wv1 = (&w[1].x)[cc], wv2 = (&w[2].x)[cc], wv3 = (&w[3].x)[cc];
        float v = acc[r][cc];
        v = fmaf(av0, wv0, v);
        v = fmaf(av1, wv1, v);
        v = fmaf(av2, wv2, v);
        v = fmaf(av3, wv3, v);
        acc[r][cc] = v;
      }
    }
  }
  float4 b = *(const float4*)&bias[c0];
#pragma unroll
  for (int r = 0; r < 4; ++r) {
    int row = row0 + r0 + r;
    if (row < N) {
      float dv = dinv[row];
      float v0 = fmaxf(acc[r][0] + b.x, 0.f) * dv;
      float v1 = fmaxf(acc[r][1] + b.y, 0.f) * dv;
      float v2 = fmaxf(acc[r][2] + b.z, 0.f) * dv;
      float v3 = fmaxf(acc[r][3] + b.w, 0.f) * dv;
      uint2 u;
      u.x = pack_bf16(v0, v1);
      u.y = pack_bf16(v2, v3);
      *(uint2*)&outb[(size_t)row * 64 + (c0 >> 1)] = u;
    }
  }
}

// heads: A packed bf16; cols 0-63 -> mu, cols 64-127 -> std (fp32 out)
__global__ __launch_bounds__(256) void k_gemm_dual_bf16(const unsigned* __restrict__ Ab,
                                                        const float* __restrict__ Wmu,
                                                        const float* __restrict__ Wstd,
                                                        const float* __restrict__ bmu,
                                                        const float* __restrict__ bstd,
                                                        float* __restrict__ out) {
  __shared__ __align__(16) float Wl[128][128];
  __shared__ __align__(16) float Al[32][128];
  const int tid = threadIdx.x;

  {
    const float4* Wm4 = (const float4*)Wmu;
    const float4* Ws4 = (const float4*)Wstd;
#pragma unroll
    for (int i = 0; i < 8; ++i) {
      int idx = tid + i * 256;
      int k = idx >> 4;
      int c4 = idx & 15;
      *(float4*)&Wl[k][c4 * 4] = Wm4[idx];
      *(float4*)&Wl[k][64 + c4 * 4] = Ws4[idx];
    }
  }
  const int row0 = blockIdx.x * 32;
  {  // A tile: unpack bf16 -> fp32 LDS
#pragma unroll
    for (int i = 0; i < 2; ++i) {
      int idx = tid + i * 256;
      int r = idx >> 4, c4 = idx & 15;
      uint4 v = make_uint4(0u, 0u, 0u, 0u);
      if (row0 + r < N) v = *(const uint4*)&Ab[(size_t)(row0 + r) * 64 + c4 * 4];
      float* dp = &Al[r][c4 * 8];
      dp[0] = blo(v.x); dp[1] = bhi(v.x);
      dp[2] = blo(v.y); dp[3] = bhi(v.y);
      dp[4] = blo(v.z); dp[5] = bhi(v.z);
      dp[6] = blo(v.w); dp[7] = bhi(v.w);
    }
  }
  __syncthreads();

  const int c0 = (tid & 31) * 4;
  const int r0 = (tid >> 5) * 4;
  float acc[4][4] = {};
  for (int k4 = 0; k4 < 32; ++k4) {
    float4 a[4];
#pragma unroll
    for (int r = 0; r < 4; ++r) a[r] = *(const float4*)&Al[r0 + r][k4 * 4];
    float4 w[4];
#pragma unroll
    for (int kk = 0; kk < 4; ++kk) w[kk] = *(const float4*)&Wl[k4 * 4 + kk][c0];
#pragma unroll
    for (int r = 0; r < 4; ++r) {
      float av0 = a[r].x, av1 = a[r].y, av2 = a[r].z, av3 = a[r].w;
#pragma unroll
      for (int cc = 0; cc < 4; ++cc) {
        float wv0 = (&w[0].x)[cc], wv1 = (&w[1].x)[cc], wv2 = (&w[2].x)[cc], wv3 = (&w[3].x)[cc];
        float v = acc[r][cc];
        v = fmaf(av0, wv0, v);
        v = fmaf(av1, wv1, v);
        v = fmaf(av2, wv2, v);
        v = fmaf(av3, wv3, v);
        acc[r][cc] = v;
      }
    }
  }
  const bool is_mu = (c0 < DO);
  const int cc0 = is_mu ? c0 : (c0 - DO);
  const float* bsel = is_mu ? bmu : bstd;
  float4 b = *(const float4*)&bsel[cc0];
  float* base = is_mu ? out : (out + (size_t)N * DO);
#pragma unroll
  for (int r = 0; r < 4; ++r) {
    int row = row0 + r0 + r;
    if (row < N) {
      float4 v;
      v.x = acc[r][0] + b.x; v.y = acc[r][1] + b.y;
      v.z = acc[r][2] + b.z; v.w = acc[r][3] + b.w;
      *(float4*)&base[(size_t)row * DO + cc0] = v;
    }
  }
}

// ---------------- launcher ----------------

static inline char* align256(char* p) {
  return (char*)(((uintptr_t)p + 255) & ~(uintptr_t)255);
}

extern "C" void kernel_launch(void* const* d_in, const int* in_sizes, int n_in,
                              void* d_out, int out_size, void* d_ws, size_t ws_size,
                              hipStream_t stream) {
  const float* x    = (const float*)d_in[0];
  const int*   ei   = (const int*)d_in[1];     // [2, E] int32
  const float* ew   = (const float*)d_in[2];
  const float* W1   = (const float*)d_in[3];
  const float* b1   = (const float*)d_in[4];
  const float* W2   = (const float*)d_in[5];
  const float* b2   = (const float*)d_in[6];
  const float* Wmu  = (const float*)d_in[7];
  const float* bmu  = (const float*)d_in[8];
  const float* Wstd = (const float*)d_in[9];
  const float* bstd = (const float*)d_in[10];
  float* out = (float*)d_out;

  const int* srcI = ei;
  const int* dstI = ei + E;

  char* p = (char*)d_ws;
  float*    dinv = (float*)p;     p = align256(p + (size_t)N * 4);
  int*      cnt  = (int*)p;       p = align256(p + (size_t)N * 4);
  int2*     ell  = (int2*)p;      p = align256(p + (size_t)N * CAP * 8);  // 25.6 MB
  unsigned* bhs  = (unsigned*)p;  p = align256(p + (size_t)N * 64 * 4);   // 12.8 MB
  unsigned* bfA  = (unsigned*)p;  p = align256(p + (size_t)N * 64 * 4);   // 12.8 MB

  dim3 blk(256);
  const int gN    = (N + 255) / 256;
  const int gE    = (E + 255) / 256;
  const int gAgg  = (N + 3) / 4;
  const int gGemm = (N + 31) / 32;

  // graph precompute: zero -> single-pass ELL build -> deg/dinv/cast
  k_zero<<<gN, blk, 0, stream>>>(cnt);
  k_build_ell<<<gE, blk, 0, stream>>>(srcI, dstI, ew, cnt, ell);
  k_degcast<<<gAgg, blk, 0, stream>>>(x, cnt, ell, dinv, bhs);

  // layer 1: h1 = relu(A(x) @ W1 + b1)
  k_agg_bf16<<<gAgg, blk, 0, stream>>>(bhs, cnt, ell, dinv, bfA);
  k_gemm_relu_bf16<<<gGemm, blk, 0, stream>>>(bfA, W1, b1, dinv, bhs);

  // layer 2: h2 = relu(A(h1) @ W2 + b2)
  k_agg_bf16<<<gAgg, blk, 0, stream>>>(bhs, cnt, ell, dinv, bfA);
  k_gemm_relu_bf16<<<gGemm, blk, 0, stream>>>(bfA, W2, b2, dinv, bhs);

  // heads: one shared aggregation (bf16 out), dual projection
  k_agg_bf16<<<gAgg, blk, 0, stream>>>(bhs, cnt, ell, dinv, bfA);
  k_gemm_dual_bf16<<<gGemm, blk, 0, stream>>>(bfA, Wmu, Wstd, bmu, bstd, out);
}